// Round 11
// baseline (276.436 us; speedup 1.0000x reference)
//
#include <hip/hip_runtime.h>
#include <hip/hip_bf16.h>

using bf16 = __hip_bfloat16;
typedef __attribute__((ext_vector_type(8))) short bf16x8;
typedef __attribute__((ext_vector_type(4))) float f32x4;
typedef __attribute__((ext_vector_type(4))) int i32x4;

#define DECAY 0.25f

// ---------------------------------------------------------------- helpers
__device__ __forceinline__ void gload_lds16(const void* g, void* l) {
  __builtin_amdgcn_global_load_lds(
      (const __attribute__((address_space(1))) void*)g,
      (__attribute__((address_space(3))) void*)l, 16, 0, 0);
}

__device__ __forceinline__ unsigned short f2bf(float f) {
  __hip_bfloat16 h = __float2bfloat16(f);
  return *reinterpret_cast<unsigned short*>(&h);
}

// ---------------------------------------------------------------- prep kernels
__global__ void cast_x_k(const float4* __restrict__ x, ushort4* __restrict__ xb, int n4) {
  int i = blockIdx.x * blockDim.x + threadIdx.x;
  int stride = gridDim.x * blockDim.x;
  for (; i < n4; i += stride) {
    float4 v = x[i];
    ushort4 o;
    o.x = f2bf(v.x); o.y = f2bf(v.y); o.z = f2bf(v.z); o.w = f2bf(v.w);
    xb[i] = o;
  }
}

__global__ void transpose_cast_k(const float* __restrict__ w, bf16* __restrict__ wt, int N) {
  __shared__ float t[32][33];
  int bx = blockIdx.x * 32, by = blockIdx.y * 32;
  int tx = threadIdx.x, ty = threadIdx.y;  // block (32,8)
#pragma unroll
  for (int i = 0; i < 32; i += 8)
    t[ty + i][tx] = w[(size_t)(by + ty + i) * N + bx + tx];
  __syncthreads();
#pragma unroll
  for (int i = 0; i < 32; i += 8)
    wt[(size_t)(bx + ty + i) * N + by + tx] = __float2bfloat16(t[tx][ty + i]);
}

// per-(k-slab, n) partial absmax, coalesced, atomicMax on uint bits
__global__ void colmax_part_k(const float* __restrict__ w, unsigned int* __restrict__ maxbits,
                              int N, int KCH) {
  int n = blockIdx.x * blockDim.x + threadIdx.x;
  int k0 = blockIdx.y * KCH;
  float mx = 0.f;
  for (int k = k0; k < k0 + KCH; ++k) mx = fmaxf(mx, fabsf(w[(size_t)k * N + n]));
  atomicMax(&maxbits[n], __float_as_uint(mx));
}

// w_out [K][N] f32 -> w_q8T [N][K] i8, per-n scaling (inv computed inline from maxbits)
__global__ void transpose_quant_k(const float* __restrict__ w,
                                  const unsigned int* __restrict__ maxbits,
                                  signed char* __restrict__ wq, int N, int K) {
  __shared__ float t[32][33];
  int bx = blockIdx.x * 32, by = blockIdx.y * 32;  // bx: n-range, by: k-range
  int tx = threadIdx.x, ty = threadIdx.y;          // block (32,8)
#pragma unroll
  for (int i = 0; i < 32; i += 8)
    t[ty + i][tx] = w[(size_t)(by + ty + i) * N + bx + tx];
  __syncthreads();
#pragma unroll
  for (int i = 0; i < 32; i += 8) {
    int n = bx + ty + i;
    float mx = __uint_as_float(maxbits[n]);
    float inv = (mx > 0.f) ? 127.f / mx : 0.f;
    int q = __float2int_rn(t[tx][ty + i] * inv);
    q = max(-127, min(127, q));
    wq[(size_t)n * K + by + tx] = (signed char)q;
  }
}

// ---------------------------------------------------------------- staging (FRAGMENT-MAJOR, 0 conflicts verified R3)
// frag = 16 rows x BK: byte d = f*1024 + l*16 holds src[row0+f*16+(l&15)][k0+(l>>4)*E ..+E]
// bf16: E=8 (BK=32); i8: E=16 (BK=64).
// A-plane 128 rows = 8KB (1 load/thread); B-plane 256 rows = 16KB (2 loads/thread).
__device__ __forceinline__ void stageA_bf16(const bf16* __restrict__ src, int ldk,
                                            int row0, int k0, char* plane, int tid) {
  int d = tid * 16;
  int f = d >> 10, l = (d >> 4) & 63;
  const bf16* g = src + (size_t)(row0 + f * 16 + (l & 15)) * ldk + k0 + (l >> 4) * 8;
  gload_lds16(g, plane + d);
}

__device__ __forceinline__ void stageB_bf16(const bf16* __restrict__ src, int ldk,
                                            int row0, int k0, char* plane, int tid) {
#pragma unroll
  for (int u = 0; u < 2; ++u) {
    int d = tid * 16 + u * 8192;
    int f = d >> 10, l = (d >> 4) & 63;
    const bf16* g = src + (size_t)(row0 + f * 16 + (l & 15)) * ldk + k0 + (l >> 4) * 8;
    gload_lds16(g, plane + d);
  }
}

__device__ __forceinline__ void stageA_i8(const signed char* __restrict__ src, int ldk,
                                          int row0, int k0, char* plane, int tid) {
  int d = tid * 16;
  int f = d >> 10, l = (d >> 4) & 63;
  const signed char* g = src + (size_t)(row0 + f * 16 + (l & 15)) * ldk + k0 + (l >> 4) * 16;
  gload_lds16(g, plane + d);
}

__device__ __forceinline__ void stageB_i8(const signed char* __restrict__ src, int ldk,
                                          int row0, int k0, char* plane, int tid) {
#pragma unroll
  for (int u = 0; u < 2; ++u) {
    int d = tid * 16 + u * 8192;
    int f = d >> 10, l = (d >> 4) & 63;
    const signed char* g = src + (size_t)(row0 + f * 16 + (l & 15)) * ldk + k0 + (l >> 4) * 16;
    gload_lds16(g, plane + d);
  }
}

// ---------------------------------------------------------------- GEMM1: xp = bf16(x) @ w_inT + b_in
// 128x256 tile, BK=32, 8 waves (2M x 4N, per-wave 64x64), 2 blocks/CU (the lever:
// cross-block desync hides stage/drain/barrier; m97/m114 mechanism).
// LDS buffer 24KB = A-plane(8KB)@0 | B-plane(16KB)@8192; x2 dbuf = 48KB.
// Ledger: stage(t+1)->nb issued; reads of cb into regs; MFMA; __syncthreads drains
// vmcnt(0) (nb ready) and orders WAR (nb's prior reads finished 2 barriers ago).
__global__ __launch_bounds__(512, 4) void gemm1_bf16_k(
    const bf16* __restrict__ A, const bf16* __restrict__ BT,
    bf16* __restrict__ C, const float* __restrict__ bias, int M, int N, int K) {
  __shared__ char lds[49152];
  const int tid = threadIdx.x, lane = tid & 63, w = tid >> 6;
  const int wr = w >> 2, wc = w & 3;  // 2M x 4N of 64x64
  const int tm = blockIdx.x * 128, tn = blockIdx.y * 256;
  const int ro = lane * 16;
  const int NT = K >> 5;  // 64

  f32x4 acc[4][4] = {};

  stageA_bf16(A,  K, tm, 0, lds + 0,    tid);
  stageB_bf16(BT, K, tn, 0, lds + 8192, tid);
  __syncthreads();

  for (int t = 0; t < NT; ++t) {
    const char* cb = lds + (t & 1) * 24576;
    char* nb = lds + ((t + 1) & 1) * 24576;
    if (t + 1 < NT) {  // block-uniform
      stageA_bf16(A,  K, tm, (t + 1) * 32, nb + 0,    tid);
      stageB_bf16(BT, K, tn, (t + 1) * 32, nb + 8192, tid);
    }
    bf16x8 a[4], b[4];
#pragma unroll
    for (int i = 0; i < 4; ++i) a[i] = *(const bf16x8*)(cb + (wr * 4 + i) * 1024 + ro);
#pragma unroll
    for (int j = 0; j < 4; ++j) b[j] = *(const bf16x8*)(cb + 8192 + (wc * 4 + j) * 1024 + ro);
    __builtin_amdgcn_s_setprio(1);
#pragma unroll
    for (int i = 0; i < 4; ++i)
#pragma unroll
      for (int j = 0; j < 4; ++j)
        acc[i][j] = __builtin_amdgcn_mfma_f32_16x16x32_bf16(a[i], b[j], acc[i][j], 0, 0, 0);
    __builtin_amdgcn_s_setprio(0);
    __syncthreads();
  }

  // epilogue: C/D layout col=lane&15, row=(lane>>4)*4+r  [m89]
#pragma unroll
  for (int i = 0; i < 4; ++i) {
    int m0 = tm + wr * 64 + i * 16 + (lane >> 4) * 4;
#pragma unroll
    for (int j = 0; j < 4; ++j) {
      int n = tn + wc * 64 + j * 16 + (lane & 15);
      float bb = bias[n];
#pragma unroll
      for (int r = 0; r < 4; ++r)
        C[(size_t)(m0 + r) * N + n] = __float2bfloat16(acc[i][j][r] + bb);
    }
  }
}

// ---------------------------------------------------------------- GEMM2: out = x + alpha*(spikes @ w_q8T * scale + b_out)
// i8, same 128x256 / 2-blocks-per-CU structure, BK=64, NT=32.
__global__ __launch_bounds__(512, 4) void gemm2_i8_k(
    const signed char* __restrict__ A, const signed char* __restrict__ BT,
    float* __restrict__ C, const unsigned int* __restrict__ maxbits,
    const float* __restrict__ bias, const float* __restrict__ xres,
    const float* __restrict__ alpha_p, int M, int N, int K) {
  __shared__ char lds[49152];
  const int tid = threadIdx.x, lane = tid & 63, w = tid >> 6;
  const int wr = w >> 2, wc = w & 3;
  const int tm = blockIdx.x * 128, tn = blockIdx.y * 256;
  const int ro = lane * 16;
  const int NT = K >> 6;  // 32

  i32x4 acc[4][4] = {};

  stageA_i8(A,  K, tm, 0, lds + 0,    tid);
  stageB_i8(BT, K, tn, 0, lds + 8192, tid);
  __syncthreads();

  for (int t = 0; t < NT; ++t) {
    const char* cb = lds + (t & 1) * 24576;
    char* nb = lds + ((t + 1) & 1) * 24576;
    if (t + 1 < NT) {
      stageA_i8(A,  K, tm, (t + 1) * 64, nb + 0,    tid);
      stageB_i8(BT, K, tn, (t + 1) * 64, nb + 8192, tid);
    }
    i32x4 a[4], b[4];
#pragma unroll
    for (int i = 0; i < 4; ++i) a[i] = *(const i32x4*)(cb + (wr * 4 + i) * 1024 + ro);
#pragma unroll
    for (int j = 0; j < 4; ++j) b[j] = *(const i32x4*)(cb + 8192 + (wc * 4 + j) * 1024 + ro);
    __builtin_amdgcn_s_setprio(1);
#pragma unroll
    for (int i = 0; i < 4; ++i)
#pragma unroll
      for (int j = 0; j < 4; ++j)
        acc[i][j] = __builtin_amdgcn_mfma_i32_16x16x64_i8(a[i], b[j], acc[i][j], 0, 0, 0);
    __builtin_amdgcn_s_setprio(0);
    __syncthreads();
  }

  // epilogue: out = x + alpha*(acc*scale[n] + b_out[n]); scale = maxbits/127
  float alpha = *alpha_p;
#pragma unroll
  for (int i = 0; i < 4; ++i) {
    int m0 = tm + wr * 64 + i * 16 + (lane >> 4) * 4;
#pragma unroll
    for (int j = 0; j < 4; ++j) {
      int n = tn + wc * 64 + j * 16 + (lane & 15);
      float sc = __uint_as_float(maxbits[n]) * (1.f / 127.f);
      float bb = bias[n];
#pragma unroll
      for (int r = 0; r < 4; ++r) {
        size_t idx = (size_t)(m0 + r) * N + n;
        C[idx] = xres[idx] + alpha * ((float)acc[i][j][r] * sc + bb);
      }
    }
  }
}

// ---------------------------------------------------------------- chunked LIF scan (bf16 in, u8 out)
__global__ void snn_scan_k(const bf16* __restrict__ xp, unsigned char* __restrict__ sp,
                           const float* __restrict__ thre_p,
                           int T, int H, int CHUNK, int WARM) {
  int h = blockIdx.x * blockDim.x + threadIdx.x;
  int b = blockIdx.y;
  int c = blockIdx.z;
  float thre = *thre_p;
  float l1 = thre, l2 = 2.f * thre, l3 = 3.f * thre, l4 = 4.f * thre;
  int t0 = c * CHUNK;
  int tw = t0 - WARM;
  if (tw < 0) tw = 0;
  const bf16* xcol = xp + (size_t)b * T * H + h;
  unsigned char* scol = sp + (size_t)b * T * H + h;
  float mem = 0.f;
  for (int t = tw; t < t0; ++t) {  // warmup (state error ~0.25^WARM)
    float xv = __bfloat162float(xcol[(size_t)t * H]);
    mem = DECAY * mem + xv;
    int s = (mem >= l1) + (mem >= l2) + (mem >= l3) + (mem >= l4);
    mem -= (float)s * thre;
  }
  for (int t = t0; t < t0 + CHUNK; ++t) {
    float xv = __bfloat162float(xcol[(size_t)t * H]);
    mem = DECAY * mem + xv;
    int s = (mem >= l1) + (mem >= l2) + (mem >= l3) + (mem >= l4);
    mem -= (float)s * thre;
    scol[(size_t)t * H] = (unsigned char)s;
  }
}

// ---------------------------------------------------------------- launch
extern "C" void kernel_launch(void* const* d_in, const int* in_sizes, int n_in,
                              void* d_out, int out_size, void* d_ws, size_t ws_size,
                              hipStream_t stream) {
  const float* x     = (const float*)d_in[0];
  const float* alpha = (const float*)d_in[1];
  const float* thre  = (const float*)d_in[2];
  const float* w_in  = (const float*)d_in[3];
  const float* b_in  = (const float*)d_in[4];
  const float* w_out = (const float*)d_in[5];
  const float* b_out = (const float*)d_in[6];
  float* out = (float*)d_out;

  const int B = 4, T = 2048, H = 2048;
  const int M = B * T;  // 8192
  const int K = H, N = H;

  char* ws = (char*)d_ws;
  size_t off = 0;
  bf16* xb            = (bf16*)(ws + off);         // 33.5MB
  signed char* spikes = (signed char*)(ws + off);  // alias: xb dead after GEMM1
  off += (size_t)M * K * 2;
  bf16* w_inT   = (bf16*)(ws + off);              off += (size_t)K * N * 2;  // 8.4MB
  signed char* w_q8T = (signed char*)(ws + off);  off += (size_t)K * N;      // 4.2MB
  unsigned int* qmaxbits = (unsigned int*)(ws + off); off += (size_t)N * 4;
  bf16* xp      = (bf16*)(ws + off);              off += (size_t)M * K * 2;  // 33.5MB

  cast_x_k<<<2048, 256, 0, stream>>>((const float4*)x, (ushort4*)xb, M * K / 4);

  dim3 tb(32, 8);
  dim3 tg(N / 32, K / 32);
  transpose_cast_k<<<tg, tb, 0, stream>>>(w_in, w_inT, N);

  hipMemsetAsync(qmaxbits, 0, (size_t)N * 4, stream);
  const int KCH = 128;
  dim3 cg(N / 256, K / KCH);
  colmax_part_k<<<cg, 256, 0, stream>>>(w_out, qmaxbits, N, KCH);
  transpose_quant_k<<<tg, tb, 0, stream>>>(w_out, qmaxbits, w_q8T, N, K);

  dim3 gg(M / 128, N / 256);  // 64 x 8 = 512 blocks = 2/CU
  gemm1_bf16_k<<<gg, 512, 0, stream>>>(xb, w_inT, xp, b_in, M, N, K);

  const int CHUNK = 128, WARM = 32, NC = T / CHUNK;
  dim3 sg(H / 256, B, NC);
  snn_scan_k<<<sg, 256, 0, stream>>>(xp, (unsigned char*)spikes, thre, T, H, CHUNK, WARM);

  gemm2_i8_k<<<gg, 512, 0, stream>>>(spikes, w_q8T, out, qmaxbits, b_out, x, alpha, M, N, K);
}

// Round 12
// 248.457 us; speedup vs baseline: 1.1126x; 1.1126x over previous
//
#include <hip/hip_runtime.h>
#include <hip/hip_bf16.h>

using bf16 = __hip_bfloat16;
typedef __attribute__((ext_vector_type(8))) short bf16x8;
typedef __attribute__((ext_vector_type(4))) float f32x4;
typedef __attribute__((ext_vector_type(4))) int i32x4;

#define DECAY 0.25f

// ---------------------------------------------------------------- helpers
__device__ __forceinline__ void gload_lds16(const void* g, void* l) {
  __builtin_amdgcn_global_load_lds(
      (const __attribute__((address_space(1))) void*)g,
      (__attribute__((address_space(3))) void*)l, 16, 0, 0);
}

#define CFENCE() asm volatile("" ::: "memory")
#define VMCNT4() asm volatile("s_waitcnt vmcnt(4)" ::: "memory")

__device__ __forceinline__ unsigned short f2bf(float f) {
  __hip_bfloat16 h = __float2bfloat16(f);
  return *reinterpret_cast<unsigned short*>(&h);
}

// ---------------------------------------------------------------- prep kernels
__global__ void transpose_cast_k(const float* __restrict__ w, bf16* __restrict__ wt, int N) {
  __shared__ float t[32][33];
  int bx = blockIdx.x * 32, by = blockIdx.y * 32;
  int tx = threadIdx.x, ty = threadIdx.y;  // block (32,8)
#pragma unroll
  for (int i = 0; i < 32; i += 8)
    t[ty + i][tx] = w[(size_t)(by + ty + i) * N + bx + tx];
  __syncthreads();
#pragma unroll
  for (int i = 0; i < 32; i += 8)
    wt[(size_t)(bx + ty + i) * N + by + tx] = __float2bfloat16(t[tx][ty + i]);
}

__global__ void colmax_part_k(const float* __restrict__ w, unsigned int* __restrict__ maxbits,
                              int N, int KCH) {
  int n = blockIdx.x * blockDim.x + threadIdx.x;
  int k0 = blockIdx.y * KCH;
  float mx = 0.f;
  for (int k = k0; k < k0 + KCH; ++k) mx = fmaxf(mx, fabsf(w[(size_t)k * N + n]));
  atomicMax(&maxbits[n], __float_as_uint(mx));
}

__global__ void transpose_quant_k(const float* __restrict__ w,
                                  const unsigned int* __restrict__ maxbits,
                                  signed char* __restrict__ wq, int N, int K) {
  __shared__ float t[32][33];
  int bx = blockIdx.x * 32, by = blockIdx.y * 32;  // bx: n-range, by: k-range
  int tx = threadIdx.x, ty = threadIdx.y;          // block (32,8)
#pragma unroll
  for (int i = 0; i < 32; i += 8)
    t[ty + i][tx] = w[(size_t)(by + ty + i) * N + bx + tx];
  __syncthreads();
#pragma unroll
  for (int i = 0; i < 32; i += 8) {
    int n = bx + ty + i;
    float mx = __uint_as_float(maxbits[n]);
    float inv = (mx > 0.f) ? 127.f / mx : 0.f;
    int q = __float2int_rn(t[tx][ty + i] * inv);
    q = max(-127, min(127, q));
    wq[(size_t)n * K + by + tx] = (signed char)q;
  }
}

// ---------------------------------------------------------------- staging (FRAGMENT-MAJOR, 0 conflicts verified R3)
// bf16 plane 16KB: byte d = f*1024 + l*16  <- src[row0+f*16+(l&15)][k0+(l>>4)*8 ..+8]
// i8   plane 16KB: same, E=16 (k-span 64)
// f32  plane 32KB: byte d = f*2048 + h*1024 + l*16
//                  <- src[row0+f*16+(l&15)][k0+(l>>4)*8 + h*4 ..+4]   (h = half-frag)
__device__ __forceinline__ void stageB_bf16(const bf16* __restrict__ src, int ldk,
                                            int row0, int k0, char* plane, int tid) {
#pragma unroll
  for (int u = 0; u < 2; ++u) {
    int d = tid * 16 + u * 8192;
    int f = d >> 10, l = (d >> 4) & 63;
    const bf16* g = src + (size_t)(row0 + f * 16 + (l & 15)) * ldk + k0 + (l >> 4) * 8;
    gload_lds16(g, plane + d);
  }
}

__device__ __forceinline__ void stageA_f32(const float* __restrict__ src, int ldk,
                                           int row0, int k0, char* plane, int tid) {
#pragma unroll
  for (int u = 0; u < 4; ++u) {
    int d = tid * 16 + u * 8192;
    int f = d >> 11;
    int dd = d & 2047;
    int h = dd >> 10;
    int l = (dd >> 4) & 63;
    const float* g =
        src + (size_t)(row0 + f * 16 + (l & 15)) * ldk + k0 + (l >> 4) * 8 + h * 4;
    gload_lds16(g, plane + d);
  }
}

__device__ __forceinline__ void stage_i8(const signed char* __restrict__ src, int ldk,
                                         int row0, int k0, char* plane, int tid) {
#pragma unroll
  for (int u = 0; u < 2; ++u) {
    int d = tid * 16 + u * 8192;
    int f = d >> 10, l = (d >> 4) & 63;
    const signed char* g = src + (size_t)(row0 + f * 16 + (l & 15)) * ldk + k0 + (l >> 4) * 16;
    gload_lds16(g, plane + d);
  }
}

// ---------------------------------------------------------------- GEMM1: xp = bf16(x) @ w_inT + b_in   (fused f32->bf16 cast)
// 256x256 tile, BK=32, 8 waves (2Mx4N, per-wave 128x64), m97 1-barrier dbuf loop.
// LDS buffer 48KB = A_f32(32KB)@0 | B_bf16(16KB)@32768; x2 = 96KB.
// A is read LDS->reg as f32 and converted to bf16 in-register (identical rounding
// to the old cast_x path -> bit-identical output). Serialization-bound regime:
// the extra ds_reads + cvts land in idle pipe time.
__global__ __launch_bounds__(512, 1) void gemm1_f32a_k(
    const float* __restrict__ X, const bf16* __restrict__ BT,
    bf16* __restrict__ C, const float* __restrict__ bias, int M, int N, int K) {
  __shared__ char lds[98304];
  const int tid = threadIdx.x, lane = tid & 63, w = tid >> 6;
  const int wr = w >> 2, wc = w & 3;  // 2M x 4N, per-wave 128x64
  const int tm = blockIdx.x * 256, tn = blockIdx.y * 256;
  const int ro = lane * 16;
  const int NT = K >> 5;  // 64

  f32x4 acc[8][4] = {};

  stageA_f32(X,  K, tm, 0, lds + 0,     tid);
  stageB_bf16(BT, K, tn, 0, lds + 32768, tid);
  __syncthreads();

  for (int t = 0; t < NT; ++t) {
    const char* cb = lds + (t & 1) * 49152;
    char* nb = lds + ((t + 1) & 1) * 49152;
    if (t + 1 < NT) {  // block-uniform
      stageA_f32(X,  K, tm, (t + 1) * 32, nb + 0,     tid);
      stageB_bf16(BT, K, tn, (t + 1) * 32, nb + 32768, tid);
    }
    const char* ab = cb + wr * 8 * 2048;
    const char* bb = cb + 32768 + wc * 4096;
    bf16x8 a[8], b[4];
#pragma unroll
    for (int j = 0; j < 4; ++j) b[j] = *(const bf16x8*)(bb + j * 1024 + ro);
#pragma unroll
    for (int i = 0; i < 8; ++i) {
      f32x4 lo = *(const f32x4*)(ab + i * 2048 + ro);
      f32x4 hi = *(const f32x4*)(ab + i * 2048 + 1024 + ro);
      bf16x8 v;
      v[0] = (short)f2bf(lo[0]); v[1] = (short)f2bf(lo[1]);
      v[2] = (short)f2bf(lo[2]); v[3] = (short)f2bf(lo[3]);
      v[4] = (short)f2bf(hi[0]); v[5] = (short)f2bf(hi[1]);
      v[6] = (short)f2bf(hi[2]); v[7] = (short)f2bf(hi[3]);
      a[i] = v;
    }
    __builtin_amdgcn_s_setprio(1);
#pragma unroll
    for (int i = 0; i < 8; ++i)
#pragma unroll
      for (int j = 0; j < 4; ++j)
        acc[i][j] = __builtin_amdgcn_mfma_f32_16x16x32_bf16(a[i], b[j], acc[i][j], 0, 0, 0);
    __builtin_amdgcn_s_setprio(0);
    __syncthreads();  // full drain: stage(t+1) published; WAR closed (reads done pre-MFMA)
  }

  // epilogue: C/D layout col=lane&15, row=(lane>>4)*4+r  [m89]
#pragma unroll
  for (int i = 0; i < 8; ++i) {
    int m0 = tm + wr * 128 + i * 16 + (lane >> 4) * 4;
#pragma unroll
    for (int j = 0; j < 4; ++j) {
      int n = tn + wc * 64 + j * 16 + (lane & 15);
      float bb = bias[n];
#pragma unroll
      for (int r = 0; r < 4; ++r)
        C[(size_t)(m0 + r) * N + n] = __float2bfloat16(acc[i][j][r] + bb);
    }
  }
}

// ---------------------------------------------------------------- GEMM2 "ring3" i8 (R10, measured-good)
// out = x + alpha*(spikes @ w_q8T * scale + b_out); BK=64, 3-buffer ring 96KB.
__global__ __launch_bounds__(512, 1) void gemm2_i8_k(
    const signed char* __restrict__ A, const signed char* __restrict__ BT,
    float* __restrict__ C, const unsigned int* __restrict__ maxbits,
    const float* __restrict__ bias, const float* __restrict__ xres,
    const float* __restrict__ alpha_p, int M, int N, int K) {
  __shared__ char lds[98304];
  const int tid = threadIdx.x, lane = tid & 63, w = tid >> 6;
  const int wr = w >> 2, wc = w & 3;
  const int tm = blockIdx.x * 256, tn = blockIdx.y * 256;
  const int ro = lane * 16;
  const int NT = K >> 6;  // 32

  i32x4 acc[8][4] = {};

  stage_i8(A,  K, tm, 0,  lds + 0,     tid);
  stage_i8(BT, K, tn, 0,  lds + 16384, tid);
  stage_i8(A,  K, tm, 64, lds + 32768 + 0,     tid);
  stage_i8(BT, K, tn, 64, lds + 32768 + 16384, tid);
  CFENCE();
  VMCNT4();
  __builtin_amdgcn_s_barrier();

  for (int t = 0; t < NT; ++t) {
    const char* cb = lds + (t % 3) * 32768;
    char* sb = lds + ((t + 2) % 3) * 32768;
    const int k2 = (t + 2 < NT ? t + 2 : NT - 1) * 64;
    stage_i8(A,  K, tm, k2, sb + 0,     tid);
    stage_i8(BT, K, tn, k2, sb + 16384, tid);
    CFENCE();
    i32x4 a[8], b[4];
#pragma unroll
    for (int j = 0; j < 4; ++j) b[j] = *(const i32x4*)(cb + 16384 + (wc * 4 + j) * 1024 + ro);
#pragma unroll
    for (int i = 0; i < 8; ++i) a[i] = *(const i32x4*)(cb + (wr * 8 + i) * 1024 + ro);
    __builtin_amdgcn_s_setprio(1);
#pragma unroll
    for (int i = 0; i < 8; ++i)
#pragma unroll
      for (int j = 0; j < 4; ++j)
        acc[i][j] = __builtin_amdgcn_mfma_i32_16x16x64_i8(a[i], b[j], acc[i][j], 0, 0, 0);
    __builtin_amdgcn_s_setprio(0);
    CFENCE();
    VMCNT4();
    __builtin_amdgcn_s_barrier();
    CFENCE();
  }

  float alpha = *alpha_p;
#pragma unroll
  for (int i = 0; i < 8; ++i) {
    int m0 = tm + wr * 128 + i * 16 + (lane >> 4) * 4;
#pragma unroll
    for (int j = 0; j < 4; ++j) {
      int n = tn + wc * 64 + j * 16 + (lane & 15);
      float sc = __uint_as_float(maxbits[n]) * (1.f / 127.f);
      float bb = bias[n];
#pragma unroll
      for (int r = 0; r < 4; ++r) {
        size_t idx = (size_t)(m0 + r) * N + n;
        C[idx] = xres[idx] + alpha * ((float)acc[i][j][r] * sc + bb);
      }
    }
  }
}

// ---------------------------------------------------------------- chunked LIF scan (bf16 in, u8 out)
__global__ void snn_scan_k(const bf16* __restrict__ xp, unsigned char* __restrict__ sp,
                           const float* __restrict__ thre_p,
                           int T, int H, int CHUNK, int WARM) {
  int h = blockIdx.x * blockDim.x + threadIdx.x;
  int b = blockIdx.y;
  int c = blockIdx.z;
  float thre = *thre_p;
  float l1 = thre, l2 = 2.f * thre, l3 = 3.f * thre, l4 = 4.f * thre;
  int t0 = c * CHUNK;
  int tw = t0 - WARM;
  if (tw < 0) tw = 0;
  const bf16* xcol = xp + (size_t)b * T * H + h;
  unsigned char* scol = sp + (size_t)b * T * H + h;
  float mem = 0.f;
  for (int t = tw; t < t0; ++t) {  // warmup (state error ~0.25^WARM)
    float xv = __bfloat162float(xcol[(size_t)t * H]);
    mem = DECAY * mem + xv;
    int s = (mem >= l1) + (mem >= l2) + (mem >= l3) + (mem >= l4);
    mem -= (float)s * thre;
  }
  for (int t = t0; t < t0 + CHUNK; ++t) {
    float xv = __bfloat162float(xcol[(size_t)t * H]);
    mem = DECAY * mem + xv;
    int s = (mem >= l1) + (mem >= l2) + (mem >= l3) + (mem >= l4);
    mem -= (float)s * thre;
    scol[(size_t)t * H] = (unsigned char)s;
  }
}

// ---------------------------------------------------------------- launch
extern "C" void kernel_launch(void* const* d_in, const int* in_sizes, int n_in,
                              void* d_out, int out_size, void* d_ws, size_t ws_size,
                              hipStream_t stream) {
  const float* x     = (const float*)d_in[0];
  const float* alpha = (const float*)d_in[1];
  const float* thre  = (const float*)d_in[2];
  const float* w_in  = (const float*)d_in[3];
  const float* b_in  = (const float*)d_in[4];
  const float* w_out = (const float*)d_in[5];
  const float* b_out = (const float*)d_in[6];
  float* out = (float*)d_out;

  const int B = 4, T = 2048, H = 2048;
  const int M = B * T;  // 8192
  const int K = H, N = H;

  char* ws = (char*)d_ws;
  size_t off = 0;
  signed char* spikes = (signed char*)(ws + off); off += (size_t)M * K;      // 16.8MB
  bf16* w_inT   = (bf16*)(ws + off);              off += (size_t)K * N * 2;  // 8.4MB
  signed char* w_q8T = (signed char*)(ws + off);  off += (size_t)K * N;      // 4.2MB
  unsigned int* qmaxbits = (unsigned int*)(ws + off); off += (size_t)N * 4;
  bf16* xp      = (bf16*)(ws + off);              off += (size_t)M * K * 2;  // 33.5MB

  dim3 tb(32, 8);
  dim3 tg(N / 32, K / 32);
  transpose_cast_k<<<tg, tb, 0, stream>>>(w_in, w_inT, N);

  hipMemsetAsync(qmaxbits, 0, (size_t)N * 4, stream);
  const int KCH = 128;
  dim3 cg(N / 256, K / KCH);
  colmax_part_k<<<cg, 256, 0, stream>>>(w_out, qmaxbits, N, KCH);
  transpose_quant_k<<<tg, tb, 0, stream>>>(w_out, qmaxbits, w_q8T, N, K);

  dim3 gg(M / 256, N / 256);  // 32 x 8 = 256 blocks
  gemm1_f32a_k<<<gg, 512, 0, stream>>>(x, w_inT, xp, b_in, M, N, K);

  const int CHUNK = 64, WARM = 24, NC = T / CHUNK;
  dim3 sg(H / 256, B, NC);
  snn_scan_k<<<sg, 256, 0, stream>>>(xp, (unsigned char*)spikes, thre, T, H, CHUNK, WARM);

  gemm2_i8_k<<<gg, 512, 0, stream>>>(spikes, w_q8T, out, qmaxbits, b_out, x, alpha, M, N, K);
}

// Round 13
// 225.911 us; speedup vs baseline: 1.2236x; 1.0998x over previous
//
#include <hip/hip_runtime.h>
#include <hip/hip_bf16.h>

using bf16 = __hip_bfloat16;
typedef __attribute__((ext_vector_type(8))) short bf16x8;
typedef __attribute__((ext_vector_type(4))) float f32x4;
typedef __attribute__((ext_vector_type(4))) int i32x4;

#define DECAY 0.25f

// ---------------------------------------------------------------- helpers
__device__ __forceinline__ void gload_lds16(const void* g, void* l) {
  __builtin_amdgcn_global_load_lds(
      (const __attribute__((address_space(1))) void*)g,
      (__attribute__((address_space(3))) void*)l, 16, 0, 0);
}

#define CFENCE() asm volatile("" ::: "memory")
#define VMCNT4() asm volatile("s_waitcnt vmcnt(4)" ::: "memory")

__device__ __forceinline__ unsigned short f2bf(float f) {
  __hip_bfloat16 h = __float2bfloat16(f);
  return *reinterpret_cast<unsigned short*>(&h);
}

// ---------------------------------------------------------------- prep kernels
__global__ void cast_x_k(const float4* __restrict__ x, ushort4* __restrict__ xb, int n4) {
  int i = blockIdx.x * blockDim.x + threadIdx.x;
  int stride = gridDim.x * blockDim.x;
  for (; i < n4; i += stride) {
    float4 v = x[i];
    ushort4 o;
    o.x = f2bf(v.x); o.y = f2bf(v.y); o.z = f2bf(v.z); o.w = f2bf(v.w);
    xb[i] = o;
  }
}

__global__ void transpose_cast_k(const float* __restrict__ w, bf16* __restrict__ wt, int N) {
  __shared__ float t[32][33];
  int bx = blockIdx.x * 32, by = blockIdx.y * 32;
  int tx = threadIdx.x, ty = threadIdx.y;  // block (32,8)
#pragma unroll
  for (int i = 0; i < 32; i += 8)
    t[ty + i][tx] = w[(size_t)(by + ty + i) * N + bx + tx];
  __syncthreads();
#pragma unroll
  for (int i = 0; i < 32; i += 8)
    wt[(size_t)(bx + ty + i) * N + by + tx] = __float2bfloat16(t[tx][ty + i]);
}

__global__ void colmax_part_k(const float* __restrict__ w, unsigned int* __restrict__ maxbits,
                              int N, int KCH) {
  int n = blockIdx.x * blockDim.x + threadIdx.x;
  int k0 = blockIdx.y * KCH;
  float mx = 0.f;
  for (int k = k0; k < k0 + KCH; ++k) mx = fmaxf(mx, fabsf(w[(size_t)k * N + n]));
  atomicMax(&maxbits[n], __float_as_uint(mx));
}

__global__ void transpose_quant_k(const float* __restrict__ w,
                                  const unsigned int* __restrict__ maxbits,
                                  signed char* __restrict__ wq, int N, int K) {
  __shared__ float t[32][33];
  int bx = blockIdx.x * 32, by = blockIdx.y * 32;  // bx: n-range, by: k-range
  int tx = threadIdx.x, ty = threadIdx.y;          // block (32,8)
#pragma unroll
  for (int i = 0; i < 32; i += 8)
    t[ty + i][tx] = w[(size_t)(by + ty + i) * N + bx + tx];
  __syncthreads();
#pragma unroll
  for (int i = 0; i < 32; i += 8) {
    int n = bx + ty + i;
    float mx = __uint_as_float(maxbits[n]);
    float inv = (mx > 0.f) ? 127.f / mx : 0.f;
    int q = __float2int_rn(t[tx][ty + i] * inv);
    q = max(-127, min(127, q));
    wq[(size_t)n * K + by + tx] = (signed char)q;
  }
}

// ---------------------------------------------------------------- staging (FRAGMENT-MAJOR, 0 conflicts verified R3)
// 16KB plane (256 rows x BK_half): byte d = f*1024 + l*16 holds
// src[row0+f*16+(l&15)][k0+(l>>4)*E ..+E]; bf16 E=8 (k-span 32), i8 E=16 (k-span 64)
__device__ __forceinline__ void stage_bf16(const bf16* __restrict__ src, int ldk,
                                           int row0, int k0, char* plane, int tid) {
#pragma unroll
  for (int u = 0; u < 2; ++u) {
    int d = tid * 16 + u * 8192;
    int f = d >> 10, l = (d >> 4) & 63;
    const bf16* g = src + (size_t)(row0 + f * 16 + (l & 15)) * ldk + k0 + (l >> 4) * 8;
    gload_lds16(g, plane + d);
  }
}

__device__ __forceinline__ void stage_i8(const signed char* __restrict__ src, int ldk,
                                         int row0, int k0, char* plane, int tid) {
#pragma unroll
  for (int u = 0; u < 2; ++u) {
    int d = tid * 16 + u * 8192;
    int f = d >> 10, l = (d >> 4) & 63;
    const signed char* g = src + (size_t)(row0 + f * 16 + (l & 15)) * ldk + k0 + (l >> 4) * 16;
    gload_lds16(g, plane + d);
  }
}

// ---------------------------------------------------------------- GEMM1 "wave-skew": xp = xb @ w_inT + b_in
// 256x256 tile, BK=64, 8 waves (2Mx4N, per-wave 128x64), dbuf 2x64KB = 128KB.
// Buffer: A kh0@0, A kh1@16384, B kh0@32768, B kh1@49152.
// ANTI-PHASE: group g = wr; kh = kk ^ g. Waves 0-3 process kh {0,1}, waves 4-7
// {1,0}. Wave->SIMD round-robin puts one wave of each group per SIMD, so one
// group's LDS read-burst overlaps the other group's MFMA-burst (the measured
// serialization: reads ~1150cyc + MFMA ~1242cyc ran back-to-back in lockstep).
// Plain full-drain __syncthreads dbuf: trivially race-free.
__global__ __launch_bounds__(512, 1) void gemm1_bf16_k(
    const bf16* __restrict__ A, const bf16* __restrict__ BT,
    bf16* __restrict__ C, const float* __restrict__ bias, int M, int N, int K) {
  __shared__ char lds[131072];
  const int tid = threadIdx.x, lane = tid & 63, w = tid >> 6;
  const int wr = w >> 2, wc = w & 3;  // 2M x 4N, per-wave 128x64
  const int grp = wr;
  const int tm = blockIdx.x * 256, tn = blockIdx.y * 256;
  const int ro = lane * 16;
  const int NT = K >> 6;  // 32

  f32x4 acc[8][4] = {};

  stage_bf16(A,  K, tm, 0,  lds + 0,     tid);
  stage_bf16(A,  K, tm, 32, lds + 16384, tid);
  stage_bf16(BT, K, tn, 0,  lds + 32768, tid);
  stage_bf16(BT, K, tn, 32, lds + 49152, tid);
  __syncthreads();

  for (int t = 0; t < NT; ++t) {
    const char* cb = lds + (t & 1) * 65536;
    char* nb = lds + ((t + 1) & 1) * 65536;
    if (t + 1 < NT) {  // block-uniform
      int k1 = (t + 1) * 64;
      stage_bf16(A,  K, tm, k1,      nb + 0,     tid);
      stage_bf16(A,  K, tm, k1 + 32, nb + 16384, tid);
      stage_bf16(BT, K, tn, k1,      nb + 32768, tid);
      stage_bf16(BT, K, tn, k1 + 32, nb + 49152, tid);
    }
#pragma unroll
    for (int kk = 0; kk < 2; ++kk) {
      const int kh = kk ^ grp;  // anti-phase between wave groups
      const char* ap = cb + kh * 16384;
      const char* bp = cb + 32768 + kh * 16384;
      bf16x8 a[8], b[4];
#pragma unroll
      for (int j = 0; j < 4; ++j) b[j] = *(const bf16x8*)(bp + (wc * 4 + j) * 1024 + ro);
#pragma unroll
      for (int i = 0; i < 8; ++i) a[i] = *(const bf16x8*)(ap + (wr * 8 + i) * 1024 + ro);
      __builtin_amdgcn_s_setprio(1);
#pragma unroll
      for (int i = 0; i < 8; ++i)
#pragma unroll
        for (int j = 0; j < 4; ++j)
          acc[i][j] = __builtin_amdgcn_mfma_f32_16x16x32_bf16(a[i], b[j], acc[i][j], 0, 0, 0);
      __builtin_amdgcn_s_setprio(0);
    }
    __syncthreads();  // full drain: stage(t+1) published; WAR closed (reads pre-MFMA)
  }

  // epilogue: C/D layout col=lane&15, row=(lane>>4)*4+r  [m89]
#pragma unroll
  for (int i = 0; i < 8; ++i) {
    int m0 = tm + wr * 128 + i * 16 + (lane >> 4) * 4;
#pragma unroll
    for (int j = 0; j < 4; ++j) {
      int n = tn + wc * 64 + j * 16 + (lane & 15);
      float bb = bias[n];
#pragma unroll
      for (int r = 0; r < 4; ++r)
        C[(size_t)(m0 + r) * N + n] = __float2bfloat16(acc[i][j][r] + bb);
    }
  }
}

// ---------------------------------------------------------------- GEMM2 "ring3" i8 (R10, measured-good)
// out = x + alpha*(spikes @ w_q8T * scale + b_out); BK=64, 3-buffer ring 96KB.
__global__ __launch_bounds__(512, 1) void gemm2_i8_k(
    const signed char* __restrict__ A, const signed char* __restrict__ BT,
    float* __restrict__ C, const unsigned int* __restrict__ maxbits,
    const float* __restrict__ bias, const float* __restrict__ xres,
    const float* __restrict__ alpha_p, int M, int N, int K) {
  __shared__ char lds[98304];
  const int tid = threadIdx.x, lane = tid & 63, w = tid >> 6;
  const int wr = w >> 2, wc = w & 3;
  const int tm = blockIdx.x * 256, tn = blockIdx.y * 256;
  const int ro = lane * 16;
  const int NT = K >> 6;  // 32

  i32x4 acc[8][4] = {};

  stage_i8(A,  K, tm, 0,  lds + 0,     tid);
  stage_i8(BT, K, tn, 0,  lds + 16384, tid);
  stage_i8(A,  K, tm, 64, lds + 32768 + 0,     tid);
  stage_i8(BT, K, tn, 64, lds + 32768 + 16384, tid);
  CFENCE();
  VMCNT4();
  __builtin_amdgcn_s_barrier();

  for (int t = 0; t < NT; ++t) {
    const char* cb = lds + (t % 3) * 32768;
    char* sb = lds + ((t + 2) % 3) * 32768;
    const int k2 = (t + 2 < NT ? t + 2 : NT - 1) * 64;
    stage_i8(A,  K, tm, k2, sb + 0,     tid);
    stage_i8(BT, K, tn, k2, sb + 16384, tid);
    CFENCE();
    i32x4 a[8], b[4];
#pragma unroll
    for (int j = 0; j < 4; ++j) b[j] = *(const i32x4*)(cb + 16384 + (wc * 4 + j) * 1024 + ro);
#pragma unroll
    for (int i = 0; i < 8; ++i) a[i] = *(const i32x4*)(cb + (wr * 8 + i) * 1024 + ro);
    __builtin_amdgcn_s_setprio(1);
#pragma unroll
    for (int i = 0; i < 8; ++i)
#pragma unroll
      for (int j = 0; j < 4; ++j)
        acc[i][j] = __builtin_amdgcn_mfma_i32_16x16x64_i8(a[i], b[j], acc[i][j], 0, 0, 0);
    __builtin_amdgcn_s_setprio(0);
    CFENCE();
    VMCNT4();
    __builtin_amdgcn_s_barrier();
    CFENCE();
  }

  float alpha = *alpha_p;
#pragma unroll
  for (int i = 0; i < 8; ++i) {
    int m0 = tm + wr * 128 + i * 16 + (lane >> 4) * 4;
#pragma unroll
    for (int j = 0; j < 4; ++j) {
      int n = tn + wc * 64 + j * 16 + (lane & 15);
      float sc = __uint_as_float(maxbits[n]) * (1.f / 127.f);
      float bb = bias[n];
#pragma unroll
      for (int r = 0; r < 4; ++r) {
        size_t idx = (size_t)(m0 + r) * N + n;
        C[idx] = xres[idx] + alpha * ((float)acc[i][j][r] * sc + bb);
      }
    }
  }
}

// ---------------------------------------------------------------- chunked LIF scan (bf16 in, u8 out)
__global__ void snn_scan_k(const bf16* __restrict__ xp, unsigned char* __restrict__ sp,
                           const float* __restrict__ thre_p,
                           int T, int H, int CHUNK, int WARM) {
  int h = blockIdx.x * blockDim.x + threadIdx.x;
  int b = blockIdx.y;
  int c = blockIdx.z;
  float thre = *thre_p;
  float l1 = thre, l2 = 2.f * thre, l3 = 3.f * thre, l4 = 4.f * thre;
  int t0 = c * CHUNK;
  int tw = t0 - WARM;
  if (tw < 0) tw = 0;
  const bf16* xcol = xp + (size_t)b * T * H + h;
  unsigned char* scol = sp + (size_t)b * T * H + h;
  float mem = 0.f;
  for (int t = tw; t < t0; ++t) {  // warmup (state error ~0.25^WARM)
    float xv = __bfloat162float(xcol[(size_t)t * H]);
    mem = DECAY * mem + xv;
    int s = (mem >= l1) + (mem >= l2) + (mem >= l3) + (mem >= l4);
    mem -= (float)s * thre;
  }
  for (int t = t0; t < t0 + CHUNK; ++t) {
    float xv = __bfloat162float(xcol[(size_t)t * H]);
    mem = DECAY * mem + xv;
    int s = (mem >= l1) + (mem >= l2) + (mem >= l3) + (mem >= l4);
    mem -= (float)s * thre;
    scol[(size_t)t * H] = (unsigned char)s;
  }
}

// ---------------------------------------------------------------- launch
extern "C" void kernel_launch(void* const* d_in, const int* in_sizes, int n_in,
                              void* d_out, int out_size, void* d_ws, size_t ws_size,
                              hipStream_t stream) {
  const float* x     = (const float*)d_in[0];
  const float* alpha = (const float*)d_in[1];
  const float* thre  = (const float*)d_in[2];
  const float* w_in  = (const float*)d_in[3];
  const float* b_in  = (const float*)d_in[4];
  const float* w_out = (const float*)d_in[5];
  const float* b_out = (const float*)d_in[6];
  float* out = (float*)d_out;

  const int B = 4, T = 2048, H = 2048;
  const int M = B * T;  // 8192
  const int K = H, N = H;

  char* ws = (char*)d_ws;
  size_t off = 0;
  bf16* xb            = (bf16*)(ws + off);         // 33.5MB
  signed char* spikes = (signed char*)(ws + off);  // alias: xb dead after GEMM1
  off += (size_t)M * K * 2;
  bf16* w_inT   = (bf16*)(ws + off);              off += (size_t)K * N * 2;  // 8.4MB
  signed char* w_q8T = (signed char*)(ws + off);  off += (size_t)K * N;      // 4.2MB
  unsigned int* qmaxbits = (unsigned int*)(ws + off); off += (size_t)N * 4;
  bf16* xp      = (bf16*)(ws + off);              off += (size_t)M * K * 2;  // 33.5MB

  cast_x_k<<<2048, 256, 0, stream>>>((const float4*)x, (ushort4*)xb, M * K / 4);

  dim3 tb(32, 8);
  dim3 tg(N / 32, K / 32);
  transpose_cast_k<<<tg, tb, 0, stream>>>(w_in, w_inT, N);

  hipMemsetAsync(qmaxbits, 0, (size_t)N * 4, stream);
  const int KCH = 128;
  dim3 cg(N / 256, K / KCH);
  colmax_part_k<<<cg, 256, 0, stream>>>(w_out, qmaxbits, N, KCH);
  transpose_quant_k<<<tg, tb, 0, stream>>>(w_out, qmaxbits, w_q8T, N, K);

  dim3 gg(M / 256, N / 256);  // 32 x 8 = 256 blocks
  gemm1_bf16_k<<<gg, 512, 0, stream>>>(xb, w_inT, xp, b_in, M, N, K);

  const int CHUNK = 64, WARM = 24, NC = T / CHUNK;
  dim3 sg(H / 256, B, NC);
  snn_scan_k<<<sg, 256, 0, stream>>>(xp, (unsigned char*)spikes, thre, T, H, CHUNK, WARM);

  gemm2_i8_k<<<gg, 512, 0, stream>>>(spikes, w_q8T, out, qmaxbits, b_out, x, alpha, M, N, K);
}

// Round 14
// 218.502 us; speedup vs baseline: 1.2651x; 1.0339x over previous
//
#include <hip/hip_runtime.h>
#include <hip/hip_bf16.h>

using bf16 = __hip_bfloat16;
typedef __attribute__((ext_vector_type(8))) short bf16x8;
typedef __attribute__((ext_vector_type(4))) float f32x4;
typedef __attribute__((ext_vector_type(4))) int i32x4;

#define DECAY 0.25f

// ---------------------------------------------------------------- helpers
__device__ __forceinline__ void gload_lds16(const void* g, void* l) {
  __builtin_amdgcn_global_load_lds(
      (const __attribute__((address_space(1))) void*)g,
      (__attribute__((address_space(3))) void*)l, 16, 0, 0);
}

__device__ __forceinline__ unsigned short f2bf(float f) {
  __hip_bfloat16 h = __float2bfloat16(f);
  return *reinterpret_cast<unsigned short*>(&h);
}

// ---------------------------------------------------------------- prep kernels
__global__ void cast_x_k(const float4* __restrict__ x, ushort4* __restrict__ xb, int n4) {
  int i = blockIdx.x * blockDim.x + threadIdx.x;
  int stride = gridDim.x * blockDim.x;
  for (; i < n4; i += stride) {
    float4 v = x[i];
    ushort4 o;
    o.x = f2bf(v.x); o.y = f2bf(v.y); o.z = f2bf(v.z); o.w = f2bf(v.w);
    xb[i] = o;
  }
}

__global__ void transpose_cast_k(const float* __restrict__ w, bf16* __restrict__ wt, int N) {
  __shared__ float t[32][33];
  int bx = blockIdx.x * 32, by = blockIdx.y * 32;
  int tx = threadIdx.x, ty = threadIdx.y;  // block (32,8)
#pragma unroll
  for (int i = 0; i < 32; i += 8)
    t[ty + i][tx] = w[(size_t)(by + ty + i) * N + bx + tx];
  __syncthreads();
#pragma unroll
  for (int i = 0; i < 32; i += 8)
    wt[(size_t)(bx + ty + i) * N + by + tx] = __float2bfloat16(t[tx][ty + i]);
}

__global__ void colmax_part_k(const float* __restrict__ w, unsigned int* __restrict__ maxbits,
                              int N, int KCH) {
  int n = blockIdx.x * blockDim.x + threadIdx.x;
  int k0 = blockIdx.y * KCH;
  float mx = 0.f;
  for (int k = k0; k < k0 + KCH; ++k) mx = fmaxf(mx, fabsf(w[(size_t)k * N + n]));
  atomicMax(&maxbits[n], __float_as_uint(mx));
}

__global__ void transpose_quant_k(const float* __restrict__ w,
                                  const unsigned int* __restrict__ maxbits,
                                  signed char* __restrict__ wq, int N, int K) {
  __shared__ float t[32][33];
  int bx = blockIdx.x * 32, by = blockIdx.y * 32;  // bx: n-range, by: k-range
  int tx = threadIdx.x, ty = threadIdx.y;          // block (32,8)
#pragma unroll
  for (int i = 0; i < 32; i += 8)
    t[ty + i][tx] = w[(size_t)(by + ty + i) * N + bx + tx];
  __syncthreads();
#pragma unroll
  for (int i = 0; i < 32; i += 8) {
    int n = bx + ty + i;
    float mx = __uint_as_float(maxbits[n]);
    float inv = (mx > 0.f) ? 127.f / mx : 0.f;
    int q = __float2int_rn(t[tx][ty + i] * inv);
    q = max(-127, min(127, q));
    wq[(size_t)n * K + by + tx] = (signed char)q;
  }
}

// ---------------------------------------------------------------- staging: ROW-MAJOR + XOR pre-swizzled source
// Region = [256 rows][128 B] = 32 KB (bf16: BK=64; i8: BK=128). LDS dest LINEAR
// (gload_lds constraint); the XOR permutation lives in the global source k-chunk:
//   dest byte d: row = d>>7, c16 = (d>>4)&7, src chunk = c16 ^ (row&7).
// Each 8-lane group covers one full 128B row (permuted within) -> coalesced.
// Reads apply the same XOR -> <=2-way bank aliasing (free, m136).
__device__ __forceinline__ void stage_row_bf16(const bf16* __restrict__ src, int ldk,
                                               int row0, int k0, char* region, int tid) {
#pragma unroll
  for (int u = 0; u < 4; ++u) {
    int d = tid * 16 + u * 8192;
    int row = d >> 7;
    int sc = ((d >> 4) & 7) ^ (row & 7);
    const bf16* g = src + (size_t)(row0 + row) * ldk + k0 + sc * 8;
    gload_lds16(g, region + d);
  }
}

__device__ __forceinline__ void stage_row_i8(const signed char* __restrict__ src, int ldk,
                                             int row0, int k0, char* region, int tid) {
#pragma unroll
  for (int u = 0; u < 4; ++u) {
    int d = tid * 16 + u * 8192;
    int row = d >> 7;
    int sc = ((d >> 4) & 7) ^ (row & 7);
    const signed char* g = src + (size_t)(row0 + row) * ldk + k0 + sc * 16;
    gload_lds16(g, region + d);
  }
}

// swizzled read address: row-local row r, k-chunk c16 (0..7)
__device__ __forceinline__ const char* swz(const char* region, int r, int c16) {
  return region + r * 128 + (((c16 ^ (r & 7)) & 7) << 4);
}

// ---------------------------------------------------------------- GEMM1: xp = xb @ w_inT + b_in
// 256x256 tile, BK=64, 8 waves (2Mx4N, per-wave 128x64), full-drain dbuf (R8 skeleton),
// row-major XOR-swizzled LDS (coalesced staging + conflict-free reads).
// LDS buffer 64KB = A[256][64]bf16 @0 | B @32768; x2 = 128KB.
__global__ __launch_bounds__(512, 1) void gemm1_bf16_k(
    const bf16* __restrict__ A, const bf16* __restrict__ BT,
    bf16* __restrict__ C, const float* __restrict__ bias, int M, int N, int K) {
  __shared__ char lds[131072];
  const int tid = threadIdx.x, lane = tid & 63, w = tid >> 6;
  const int wr = w >> 2, wc = w & 3;  // 2M x 4N, per-wave 128x64
  const int tm = blockIdx.x * 256, tn = blockIdx.y * 256;
  const int lr = lane & 15;       // row-within-frag
  const int lc = lane >> 4;       // k-chunk base (0..3)
  const int NT = K >> 6;  // 32

  f32x4 acc[8][4] = {};

  stage_row_bf16(A,  K, tm, 0, lds + 0,     tid);
  stage_row_bf16(BT, K, tn, 0, lds + 32768, tid);
  __syncthreads();

  for (int t = 0; t < NT; ++t) {
    const char* cb = lds + (t & 1) * 65536;
    char* nb = lds + ((t + 1) & 1) * 65536;
    if (t + 1 < NT) {  // block-uniform
      stage_row_bf16(A,  K, tm, (t + 1) * 64, nb + 0,     tid);
      stage_row_bf16(BT, K, tn, (t + 1) * 64, nb + 32768, tid);
    }
#pragma unroll
    for (int kh = 0; kh < 2; ++kh) {
      const int c16 = lc + kh * 4;
      bf16x8 a[8], b[4];
#pragma unroll
      for (int j = 0; j < 4; ++j)
        b[j] = *(const bf16x8*)swz(cb + 32768, wc * 64 + j * 16 + lr, c16);
#pragma unroll
      for (int i = 0; i < 8; ++i)
        a[i] = *(const bf16x8*)swz(cb, wr * 128 + i * 16 + lr, c16);
      __builtin_amdgcn_s_setprio(1);
#pragma unroll
      for (int i = 0; i < 8; ++i)
#pragma unroll
        for (int j = 0; j < 4; ++j)
          acc[i][j] = __builtin_amdgcn_mfma_f32_16x16x32_bf16(a[i], b[j], acc[i][j], 0, 0, 0);
      __builtin_amdgcn_s_setprio(0);
    }
    __syncthreads();  // full drain: stage(t+1) published; WAR closed (reads pre-MFMA)
  }

  // epilogue: C/D layout col=lane&15, row=(lane>>4)*4+r  [m89]
#pragma unroll
  for (int i = 0; i < 8; ++i) {
    int m0 = tm + wr * 128 + i * 16 + (lane >> 4) * 4;
#pragma unroll
    for (int j = 0; j < 4; ++j) {
      int n = tn + wc * 64 + j * 16 + (lane & 15);
      float bb = bias[n];
#pragma unroll
      for (int r = 0; r < 4; ++r)
        C[(size_t)(m0 + r) * N + n] = __float2bfloat16(acc[i][j][r] + bb);
    }
  }
}

// ---------------------------------------------------------------- GEMM2: out = x + alpha*(spikes @ w_q8T * scale + b_out)
// i8, 256x256 tile, BK=128, NT=16, same row-major swizzled staging.
// LDS buffer 64KB = A[256][128]i8 @0 | B @32768; x2 = 128KB.
__global__ __launch_bounds__(512, 1) void gemm2_i8_k(
    const signed char* __restrict__ A, const signed char* __restrict__ BT,
    float* __restrict__ C, const unsigned int* __restrict__ maxbits,
    const float* __restrict__ bias, const float* __restrict__ xres,
    const float* __restrict__ alpha_p, int M, int N, int K) {
  __shared__ char lds[131072];
  const int tid = threadIdx.x, lane = tid & 63, w = tid >> 6;
  const int wr = w >> 2, wc = w & 3;
  const int tm = blockIdx.x * 256, tn = blockIdx.y * 256;
  const int lr = lane & 15;
  const int lc = lane >> 4;
  const int NT = K >> 7;  // 16

  i32x4 acc[8][4] = {};

  stage_row_i8(A,  K, tm, 0, lds + 0,     tid);
  stage_row_i8(BT, K, tn, 0, lds + 32768, tid);
  __syncthreads();

  for (int t = 0; t < NT; ++t) {
    const char* cb = lds + (t & 1) * 65536;
    char* nb = lds + ((t + 1) & 1) * 65536;
    if (t + 1 < NT) {
      stage_row_i8(A,  K, tm, (t + 1) * 128, nb + 0,     tid);
      stage_row_i8(BT, K, tn, (t + 1) * 128, nb + 32768, tid);
    }
#pragma unroll
    for (int kh = 0; kh < 2; ++kh) {
      const int c16 = lc + kh * 4;
      i32x4 a[8], b[4];
#pragma unroll
      for (int j = 0; j < 4; ++j)
        b[j] = *(const i32x4*)swz(cb + 32768, wc * 64 + j * 16 + lr, c16);
#pragma unroll
      for (int i = 0; i < 8; ++i)
        a[i] = *(const i32x4*)swz(cb, wr * 128 + i * 16 + lr, c16);
      __builtin_amdgcn_s_setprio(1);
#pragma unroll
      for (int i = 0; i < 8; ++i)
#pragma unroll
        for (int j = 0; j < 4; ++j)
          acc[i][j] = __builtin_amdgcn_mfma_i32_16x16x64_i8(a[i], b[j], acc[i][j], 0, 0, 0);
      __builtin_amdgcn_s_setprio(0);
    }
    __syncthreads();
  }

  // epilogue: out = x + alpha*(acc*scale[n] + b_out[n]); scale = maxbits/127
  float alpha = *alpha_p;
#pragma unroll
  for (int i = 0; i < 8; ++i) {
    int m0 = tm + wr * 128 + i * 16 + (lane >> 4) * 4;
#pragma unroll
    for (int j = 0; j < 4; ++j) {
      int n = tn + wc * 64 + j * 16 + (lane & 15);
      float sc = __uint_as_float(maxbits[n]) * (1.f / 127.f);
      float bb = bias[n];
#pragma unroll
      for (int r = 0; r < 4; ++r) {
        size_t idx = (size_t)(m0 + r) * N + n;
        C[idx] = xres[idx] + alpha * ((float)acc[i][j][r] * sc + bb);
      }
    }
  }
}

// ---------------------------------------------------------------- chunked LIF scan (bf16 in, u8 out)
__global__ void snn_scan_k(const bf16* __restrict__ xp, unsigned char* __restrict__ sp,
                           const float* __restrict__ thre_p,
                           int T, int H, int CHUNK, int WARM) {
  int h = blockIdx.x * blockDim.x + threadIdx.x;
  int b = blockIdx.y;
  int c = blockIdx.z;
  float thre = *thre_p;
  float l1 = thre, l2 = 2.f * thre, l3 = 3.f * thre, l4 = 4.f * thre;
  int t0 = c * CHUNK;
  int tw = t0 - WARM;
  if (tw < 0) tw = 0;
  const bf16* xcol = xp + (size_t)b * T * H + h;
  unsigned char* scol = sp + (size_t)b * T * H + h;
  float mem = 0.f;
  for (int t = tw; t < t0; ++t) {  // warmup (state error ~0.25^WARM)
    float xv = __bfloat162float(xcol[(size_t)t * H]);
    mem = DECAY * mem + xv;
    int s = (mem >= l1) + (mem >= l2) + (mem >= l3) + (mem >= l4);
    mem -= (float)s * thre;
  }
  for (int t = t0; t < t0 + CHUNK; ++t) {
    float xv = __bfloat162float(xcol[(size_t)t * H]);
    mem = DECAY * mem + xv;
    int s = (mem >= l1) + (mem >= l2) + (mem >= l3) + (mem >= l4);
    mem -= (float)s * thre;
    scol[(size_t)t * H] = (unsigned char)s;
  }
}

// ---------------------------------------------------------------- launch
extern "C" void kernel_launch(void* const* d_in, const int* in_sizes, int n_in,
                              void* d_out, int out_size, void* d_ws, size_t ws_size,
                              hipStream_t stream) {
  const float* x     = (const float*)d_in[0];
  const float* alpha = (const float*)d_in[1];
  const float* thre  = (const float*)d_in[2];
  const float* w_in  = (const float*)d_in[3];
  const float* b_in  = (const float*)d_in[4];
  const float* w_out = (const float*)d_in[5];
  const float* b_out = (const float*)d_in[6];
  float* out = (float*)d_out;

  const int B = 4, T = 2048, H = 2048;
  const int M = B * T;  // 8192
  const int K = H, N = H;

  char* ws = (char*)d_ws;
  size_t off = 0;
  bf16* xb            = (bf16*)(ws + off);         // 33.5MB
  signed char* spikes = (signed char*)(ws + off);  // alias: xb dead after GEMM1
  off += (size_t)M * K * 2;
  bf16* w_inT   = (bf16*)(ws + off);              off += (size_t)K * N * 2;  // 8.4MB
  signed char* w_q8T = (signed char*)(ws + off);  off += (size_t)K * N;      // 4.2MB
  unsigned int* qmaxbits = (unsigned int*)(ws + off); off += (size_t)N * 4;
  bf16* xp      = (bf16*)(ws + off);              off += (size_t)M * K * 2;  // 33.5MB

  cast_x_k<<<2048, 256, 0, stream>>>((const float4*)x, (ushort4*)xb, M * K / 4);

  dim3 tb(32, 8);
  dim3 tg(N / 32, K / 32);
  transpose_cast_k<<<tg, tb, 0, stream>>>(w_in, w_inT, N);

  hipMemsetAsync(qmaxbits, 0, (size_t)N * 4, stream);
  const int KCH = 128;
  dim3 cg(N / 256, K / KCH);
  colmax_part_k<<<cg, 256, 0, stream>>>(w_out, qmaxbits, N, KCH);
  transpose_quant_k<<<tg, tb, 0, stream>>>(w_out, qmaxbits, w_q8T, N, K);

  dim3 gg(M / 256, N / 256);  // 32 x 8 = 256 blocks
  gemm1_bf16_k<<<gg, 512, 0, stream>>>(xb, w_inT, xp, b_in, M, N, K);

  const int CHUNK = 128, WARM = 32, NC = T / CHUNK;
  dim3 sg(H / 256, B, NC);
  snn_scan_k<<<sg, 256, 0, stream>>>(xp, (unsigned char*)spikes, thre, T, H, CHUNK, WARM);

  gemm2_i8_k<<<gg, 512, 0, stream>>>(spikes, w_q8T, out, qmaxbits, b_out, x, alpha, M, N, K);
}

// Round 15
// 213.124 us; speedup vs baseline: 1.2971x; 1.0252x over previous
//
#include <hip/hip_runtime.h>
#include <hip/hip_bf16.h>

using bf16 = __hip_bfloat16;
typedef __attribute__((ext_vector_type(8))) short bf16x8;
typedef __attribute__((ext_vector_type(4))) float f32x4;
typedef __attribute__((ext_vector_type(4))) int i32x4;

#define DECAY 0.25f

// ---------------------------------------------------------------- helpers
__device__ __forceinline__ void gload_lds16(const void* g, void* l) {
  __builtin_amdgcn_global_load_lds(
      (const __attribute__((address_space(1))) void*)g,
      (__attribute__((address_space(3))) void*)l, 16, 0, 0);
}

__device__ __forceinline__ unsigned short f2bf(float f) {
  __hip_bfloat16 h = __float2bfloat16(f);
  return *reinterpret_cast<unsigned short*>(&h);
}

// ---------------------------------------------------------------- prep kernels
__global__ void transpose_cast_k(const float* __restrict__ w, bf16* __restrict__ wt, int N) {
  __shared__ float t[32][33];
  int bx = blockIdx.x * 32, by = blockIdx.y * 32;
  int tx = threadIdx.x, ty = threadIdx.y;  // block (32,8)
#pragma unroll
  for (int i = 0; i < 32; i += 8)
    t[ty + i][tx] = w[(size_t)(by + ty + i) * N + bx + tx];
  __syncthreads();
#pragma unroll
  for (int i = 0; i < 32; i += 8)
    wt[(size_t)(bx + ty + i) * N + by + tx] = __float2bfloat16(t[tx][ty + i]);
}

__global__ void colmax_part_k(const float* __restrict__ w, unsigned int* __restrict__ maxbits,
                              int N, int KCH) {
  int n = blockIdx.x * blockDim.x + threadIdx.x;
  int k0 = blockIdx.y * KCH;
  float mx = 0.f;
  for (int k = k0; k < k0 + KCH; ++k) mx = fmaxf(mx, fabsf(w[(size_t)k * N + n]));
  atomicMax(&maxbits[n], __float_as_uint(mx));
}

__global__ void transpose_quant_k(const float* __restrict__ w,
                                  const unsigned int* __restrict__ maxbits,
                                  signed char* __restrict__ wq, int N, int K) {
  __shared__ float t[32][33];
  int bx = blockIdx.x * 32, by = blockIdx.y * 32;  // bx: n-range, by: k-range
  int tx = threadIdx.x, ty = threadIdx.y;          // block (32,8)
#pragma unroll
  for (int i = 0; i < 32; i += 8)
    t[ty + i][tx] = w[(size_t)(by + ty + i) * N + bx + tx];
  __syncthreads();
#pragma unroll
  for (int i = 0; i < 32; i += 8) {
    int n = bx + ty + i;
    float mx = __uint_as_float(maxbits[n]);
    float inv = (mx > 0.f) ? 127.f / mx : 0.f;
    int q = __float2int_rn(t[tx][ty + i] * inv);
    q = max(-127, min(127, q));
    wq[(size_t)n * K + by + tx] = (signed char)q;
  }
}

// ---------------------------------------------------------------- staging: ROW-MAJOR + XOR pre-swizzled source (R14, verified)
// Region = [256 rows][128 B]. LDS image: byte row*128 + c16*16 holds
// src[row0+row][k0 + (c16^(row&7))*E ..+E]  (bf16 E=8, i8 E=16).
// gload variants: LINEAR LDS dest, permutation in the global source.
__device__ __forceinline__ void stage_row_bf16(const bf16* __restrict__ src, int ldk,
                                               int row0, int k0, char* region, int tid) {
#pragma unroll
  for (int u = 0; u < 4; ++u) {
    int d = tid * 16 + u * 8192;
    int row = d >> 7;
    int sc = ((d >> 4) & 7) ^ (row & 7);
    const bf16* g = src + (size_t)(row0 + row) * ldk + k0 + sc * 8;
    gload_lds16(g, region + d);
  }
}

__device__ __forceinline__ void stage_row_i8(const signed char* __restrict__ src, int ldk,
                                             int row0, int k0, char* region, int tid) {
#pragma unroll
  for (int u = 0; u < 4; ++u) {
    int d = tid * 16 + u * 8192;
    int row = d >> 7;
    int sc = ((d >> 4) & 7) ^ (row & 7);
    const signed char* g = src + (size_t)(row0 + row) * ldk + k0 + sc * 16;
    gload_lds16(g, region + d);
  }
}

// swizzled read address: row-local row r, k-chunk c16 (0..7)
__device__ __forceinline__ const char* swz(const char* region, int r, int c16) {
  return region + r * 128 + (((c16 ^ (r & 7)) & 7) << 4);
}

// ---------------------------------------------------------------- A reg-stage from f32 x (fused cast; T14 load-early/write-late)
// Pass u: row = u*64 + tid>>3, dest chunk c16 = tid&7, src chunk = c16^(row&7).
// 8 consecutive lanes cover one row's contiguous 256B f32 (permuted 32B blocks)
// -> coalesced. ds_write_b128 at lane-consecutive 16B -> conflict-free. Produces
// the exact LDS image of stage_row_bf16 (read side unchanged).
__device__ __forceinline__ void stageA_load_f32(const float* __restrict__ X, int ldk,
                                                int row0, int k0, int tid,
                                                f32x4 (&v)[4][2]) {
#pragma unroll
  for (int u = 0; u < 4; ++u) {
    int row = u * 64 + (tid >> 3);
    int sc = (tid & 7) ^ (row & 7);
    const float* g = X + (size_t)(row0 + row) * ldk + k0 + sc * 8;
    v[u][0] = *(const f32x4*)g;
    v[u][1] = *(const f32x4*)(g + 4);
  }
}

__device__ __forceinline__ void stageA_write_bf16(const f32x4 (&v)[4][2], char* region,
                                                  int tid) {
#pragma unroll
  for (int u = 0; u < 4; ++u) {
    int d = u * 8192 + tid * 16;
    bf16x8 o;
    o[0] = (short)f2bf(v[u][0][0]); o[1] = (short)f2bf(v[u][0][1]);
    o[2] = (short)f2bf(v[u][0][2]); o[3] = (short)f2bf(v[u][0][3]);
    o[4] = (short)f2bf(v[u][1][0]); o[5] = (short)f2bf(v[u][1][1]);
    o[6] = (short)f2bf(v[u][1][2]); o[7] = (short)f2bf(v[u][1][3]);
    *(bf16x8*)(region + d) = o;
  }
}

// ---------------------------------------------------------------- GEMM1: xp = bf16(x) @ w_inT + b_in   (fused f32->bf16 cast)
// 256x256 tile, BK=64, 8 waves (2Mx4N, per-wave 128x64), full-drain dbuf (R14 skeleton).
// LDS buffer 64KB = A[256][64]bf16-swz @0 | B @32768; x2 = 128KB.
// A: reg-staged from f32 x (loads at loop top, cvt+ds_write after MFMA - HBM latency
// hides under ~4700cyc compute). B: gload_lds pre-swizzled (R14). Rounding identical
// to the old cast_x path -> bit-identical output.
__global__ __launch_bounds__(512, 1) void gemm1_bf16_k(
    const float* __restrict__ X, const bf16* __restrict__ BT,
    bf16* __restrict__ C, const float* __restrict__ bias, int M, int N, int K) {
  __shared__ char lds[131072];
  const int tid = threadIdx.x, lane = tid & 63, w = tid >> 6;
  const int wr = w >> 2, wc = w & 3;  // 2M x 4N, per-wave 128x64
  const int tm = blockIdx.x * 256, tn = blockIdx.y * 256;
  const int lr = lane & 15;       // row-within-frag
  const int lc = lane >> 4;       // k-chunk base (0..3)
  const int NT = K >> 6;  // 32

  f32x4 acc[8][4] = {};

  {  // prologue: tile 0
    f32x4 av[4][2];
    stageA_load_f32(X, K, tm, 0, tid, av);
    stage_row_bf16(BT, K, tn, 0, lds + 32768, tid);
    stageA_write_bf16(av, lds + 0, tid);
    __syncthreads();
  }

  for (int t = 0; t < NT; ++t) {
    const char* cb = lds + (t & 1) * 65536;
    char* nb = lds + ((t + 1) & 1) * 65536;
    const bool pf = (t + 1 < NT);
    f32x4 av[4][2];
    if (pf) {
      stageA_load_f32(X, K, tm, (t + 1) * 64, tid, av);      // issue early
      stage_row_bf16(BT, K, tn, (t + 1) * 64, nb + 32768, tid);
    }
#pragma unroll
    for (int kh = 0; kh < 2; ++kh) {
      const int c16 = lc + kh * 4;
      bf16x8 a[8], b[4];
#pragma unroll
      for (int j = 0; j < 4; ++j)
        b[j] = *(const bf16x8*)swz(cb + 32768, wc * 64 + j * 16 + lr, c16);
#pragma unroll
      for (int i = 0; i < 8; ++i)
        a[i] = *(const bf16x8*)swz(cb, wr * 128 + i * 16 + lr, c16);
      __builtin_amdgcn_s_setprio(1);
#pragma unroll
      for (int i = 0; i < 8; ++i)
#pragma unroll
        for (int j = 0; j < 4; ++j)
          acc[i][j] = __builtin_amdgcn_mfma_f32_16x16x32_bf16(a[i], b[j], acc[i][j], 0, 0, 0);
      __builtin_amdgcn_s_setprio(0);
    }
    if (pf) stageA_write_bf16(av, nb, tid);  // cvt+write late (vmcnt wait lands here)
    __syncthreads();  // drains gloads + ds_writes; WAR closed (reads pre-MFMA)
  }

  // epilogue: C/D layout col=lane&15, row=(lane>>4)*4+r  [m89]
#pragma unroll
  for (int i = 0; i < 8; ++i) {
    int m0 = tm + wr * 128 + i * 16 + (lane >> 4) * 4;
#pragma unroll
    for (int j = 0; j < 4; ++j) {
      int n = tn + wc * 64 + j * 16 + (lane & 15);
      float bb = bias[n];
#pragma unroll
      for (int r = 0; r < 4; ++r)
        C[(size_t)(m0 + r) * N + n] = __float2bfloat16(acc[i][j][r] + bb);
    }
  }
}

// ---------------------------------------------------------------- GEMM2: out = x + alpha*(spikes @ w_q8T * scale + b_out)
// i8, 256x256 tile, BK=128, NT=16, row-major swizzled staging (R14, measured-good).
__global__ __launch_bounds__(512, 1) void gemm2_i8_k(
    const signed char* __restrict__ A, const signed char* __restrict__ BT,
    float* __restrict__ C, const unsigned int* __restrict__ maxbits,
    const float* __restrict__ bias, const float* __restrict__ xres,
    const float* __restrict__ alpha_p, int M, int N, int K) {
  __shared__ char lds[131072];
  const int tid = threadIdx.x, lane = tid & 63, w = tid >> 6;
  const int wr = w >> 2, wc = w & 3;
  const int tm = blockIdx.x * 256, tn = blockIdx.y * 256;
  const int lr = lane & 15;
  const int lc = lane >> 4;
  const int NT = K >> 7;  // 16

  i32x4 acc[8][4] = {};

  stage_row_i8(A,  K, tm, 0, lds + 0,     tid);
  stage_row_i8(BT, K, tn, 0, lds + 32768, tid);
  __syncthreads();

  for (int t = 0; t < NT; ++t) {
    const char* cb = lds + (t & 1) * 65536;
    char* nb = lds + ((t + 1) & 1) * 65536;
    if (t + 1 < NT) {
      stage_row_i8(A,  K, tm, (t + 1) * 128, nb + 0,     tid);
      stage_row_i8(BT, K, tn, (t + 1) * 128, nb + 32768, tid);
    }
#pragma unroll
    for (int kh = 0; kh < 2; ++kh) {
      const int c16 = lc + kh * 4;
      i32x4 a[8], b[4];
#pragma unroll
      for (int j = 0; j < 4; ++j)
        b[j] = *(const i32x4*)swz(cb + 32768, wc * 64 + j * 16 + lr, c16);
#pragma unroll
      for (int i = 0; i < 8; ++i)
        a[i] = *(const i32x4*)swz(cb, wr * 128 + i * 16 + lr, c16);
      __builtin_amdgcn_s_setprio(1);
#pragma unroll
      for (int i = 0; i < 8; ++i)
#pragma unroll
        for (int j = 0; j < 4; ++j)
          acc[i][j] = __builtin_amdgcn_mfma_i32_16x16x64_i8(a[i], b[j], acc[i][j], 0, 0, 0);
      __builtin_amdgcn_s_setprio(0);
    }
    __syncthreads();
  }

  // epilogue: out = x + alpha*(acc*scale[n] + b_out[n]); scale = maxbits/127
  float alpha = *alpha_p;
#pragma unroll
  for (int i = 0; i < 8; ++i) {
    int m0 = tm + wr * 128 + i * 16 + (lane >> 4) * 4;
#pragma unroll
    for (int j = 0; j < 4; ++j) {
      int n = tn + wc * 64 + j * 16 + (lane & 15);
      float sc = __uint_as_float(maxbits[n]) * (1.f / 127.f);
      float bb = bias[n];
#pragma unroll
      for (int r = 0; r < 4; ++r) {
        size_t idx = (size_t)(m0 + r) * N + n;
        C[idx] = xres[idx] + alpha * ((float)acc[i][j][r] * sc + bb);
      }
    }
  }
}

// ---------------------------------------------------------------- chunked LIF scan (bf16 in, u8 out)
__global__ void snn_scan_k(const bf16* __restrict__ xp, unsigned char* __restrict__ sp,
                           const float* __restrict__ thre_p,
                           int T, int H, int CHUNK, int WARM) {
  int h = blockIdx.x * blockDim.x + threadIdx.x;
  int b = blockIdx.y;
  int c = blockIdx.z;
  float thre = *thre_p;
  float l1 = thre, l2 = 2.f * thre, l3 = 3.f * thre, l4 = 4.f * thre;
  int t0 = c * CHUNK;
  int tw = t0 - WARM;
  if (tw < 0) tw = 0;
  const bf16* xcol = xp + (size_t)b * T * H + h;
  unsigned char* scol = sp + (size_t)b * T * H + h;
  float mem = 0.f;
  for (int t = tw; t < t0; ++t) {  // warmup (state error ~0.25^WARM)
    float xv = __bfloat162float(xcol[(size_t)t * H]);
    mem = DECAY * mem + xv;
    int s = (mem >= l1) + (mem >= l2) + (mem >= l3) + (mem >= l4);
    mem -= (float)s * thre;
  }
  for (int t = t0; t < t0 + CHUNK; ++t) {
    float xv = __bfloat162float(xcol[(size_t)t * H]);
    mem = DECAY * mem + xv;
    int s = (mem >= l1) + (mem >= l2) + (mem >= l3) + (mem >= l4);
    mem -= (float)s * thre;
    scol[(size_t)t * H] = (unsigned char)s;
  }
}

// ---------------------------------------------------------------- launch
extern "C" void kernel_launch(void* const* d_in, const int* in_sizes, int n_in,
                              void* d_out, int out_size, void* d_ws, size_t ws_size,
                              hipStream_t stream) {
  const float* x     = (const float*)d_in[0];
  const float* alpha = (const float*)d_in[1];
  const float* thre  = (const float*)d_in[2];
  const float* w_in  = (const float*)d_in[3];
  const float* b_in  = (const float*)d_in[4];
  const float* w_out = (const float*)d_in[5];
  const float* b_out = (const float*)d_in[6];
  float* out = (float*)d_out;

  const int B = 4, T = 2048, H = 2048;
  const int M = B * T;  // 8192
  const int K = H, N = H;

  char* ws = (char*)d_ws;
  size_t off = 0;
  signed char* spikes = (signed char*)(ws + off); off += (size_t)M * K;      // 16.8MB
  bf16* w_inT   = (bf16*)(ws + off);              off += (size_t)K * N * 2;  // 8.4MB
  signed char* w_q8T = (signed char*)(ws + off);  off += (size_t)K * N;      // 4.2MB
  unsigned int* qmaxbits = (unsigned int*)(ws + off); off += (size_t)N * 4;
  bf16* xp      = (bf16*)(ws + off);              off += (size_t)M * K * 2;  // 33.5MB

  dim3 tb(32, 8);
  dim3 tg(N / 32, K / 32);
  transpose_cast_k<<<tg, tb, 0, stream>>>(w_in, w_inT, N);

  hipMemsetAsync(qmaxbits, 0, (size_t)N * 4, stream);
  const int KCH = 128;
  dim3 cg(N / 256, K / KCH);
  colmax_part_k<<<cg, 256, 0, stream>>>(w_out, qmaxbits, N, KCH);
  transpose_quant_k<<<tg, tb, 0, stream>>>(w_out, qmaxbits, w_q8T, N, K);

  dim3 gg(M / 256, N / 256);  // 32 x 8 = 256 blocks
  gemm1_bf16_k<<<gg, 512, 0, stream>>>(x, w_inT, xp, b_in, M, N, K);

  const int CHUNK = 128, WARM = 32, NC = T / CHUNK;
  dim3 sg(H / 256, B, NC);
  snn_scan_k<<<sg, 256, 0, stream>>>(xp, (unsigned char*)spikes, thre, T, H, CHUNK, WARM);

  gemm2_i8_k<<<gg, 512, 0, stream>>>(spikes, w_q8T, out, qmaxbits, b_out, x, alpha, M, N, K);
}